// Round 11
// baseline (10909.515 us; speedup 1.0000x reference)
//
#include <hip/hip_runtime.h>
#include <stdint.h>

typedef unsigned short u16;
typedef __attribute__((ext_vector_type(8))) short short8v;
typedef __attribute__((ext_vector_type(4))) float f32x4;

// output layout (floats): out(8,1022,1024) | h_n(2,8,512) | c_n(2,8,512)
#define OUT_HN   8372224
#define OUT_CN   8380416

// ws layout (bytes) — total 25,182,464 B
#define WS_WIH0  0
#define WS_WIH1  (WS_WIH0 + 2097152)
#define WS_WHH0  (WS_WIH1 + 2097152)
#define WS_WHH1  (WS_WHH0 + 2097152)
#define WS_HSB0  (WS_WHH1 + 2097152)        // 1025*8*512 bf16 = 8,396,800 B
#define WS_HSB1  (WS_HSB0 + 8396800)
#define WS_FLAGS (WS_HSB1 + 8396800)        // 64 * u32

__device__ __forceinline__ u16 f2bf(float f) {
  uint32_t u = __float_as_uint(f);
  u += 0x7FFFu + ((u >> 16) & 1u);
  return (u16)(u >> 16);
}
__device__ __forceinline__ float bf2f(u16 v) {
  return __uint_as_float(((uint32_t)v) << 16);
}
__device__ __forceinline__ short8v cvtx8(const float* p) {
  float4 a = *(const float4*)p;
  float4 b = *(const float4*)(p + 4);
  short8v r;
  r[0] = (short)f2bf(a.x); r[1] = (short)f2bf(a.y);
  r[2] = (short)f2bf(a.z); r[3] = (short)f2bf(a.w);
  r[4] = (short)f2bf(b.x); r[5] = (short)f2bf(b.y);
  r[6] = (short)f2bf(b.z); r[7] = (short)f2bf(b.w);
  return r;
}

__global__ void k_f2bf(const float* __restrict__ src, u16* __restrict__ dst, int n) {
  int i = blockIdx.x * blockDim.x + threadIdx.x;
  int stride = gridDim.x * blockDim.x;
  for (; i < n; i += stride) dst[i] = f2bf(src[i]);
}

__global__ void k_init(uint32_t* flags) {
  if (threadIdx.x < 64) flags[threadIdx.x] = 0;
}

// Persistent bidirectional LSTM. grid = 32 blocks x 256 threads.
// blocks 0..15: forward, 16..31: backward. Each WG owns 32 hidden units.
// Wave w = gate w (i,f,g,o). W_ih/W_hh MFMA B-fragments resident in ~256
// VGPRs (loaded once). h broadcast via bf16 hsb[(S+1)][8][512] through LLC.
// Barrier protocol (R11): publisher = release fetch_add (wbl2 + LLC RMW);
// pollers = RELAXED agent loads (LLC-serviced, no cache maintenance per
// iteration) + ONE acquire fence after the wait. The R10 version acquired
// per poll iteration -> buffer_inv storm -> 11 us/step and 4x HBM refetch.
__launch_bounds__(256, 1)
__global__ void k_lstm(const float* __restrict__ xf,
                       const u16* __restrict__ wih0, const u16* __restrict__ wih1,
                       const u16* __restrict__ whh0, const u16* __restrict__ whh1,
                       const float* __restrict__ bias0, const float* __restrict__ bias1,
                       u16* hsb0, u16* hsb1, float* out, uint32_t* flags)
{
  const int tid  = threadIdx.x;
  const int wid  = tid >> 6;     // wave = gate
  const int lane = tid & 63;
  const int dir  = blockIdx.x >> 4;
  const int wg   = blockIdx.x & 15;
  const int jbase = wg * 32;

  const u16*  wih  = dir ? wih1  : wih0;
  const u16*  whh  = dir ? whh1  : whh0;
  const float* bias = dir ? bias1 : bias0;
  u16* hsb = dir ? hsb1 : hsb0;
  uint32_t* fl = flags + dir * 16;

  __shared__ float zL[4 * 8 * 32];   // [gate][b][jj]

  // B-fragments: lane holds W[row = g*512 + jbase + nt*16 + (lane&15)]
  //                          [k = kt*32 + (lane>>4)*8 .. +8]
  short8v bih[2][16], bhh[2][16];
  {
    const int rr = lane & 15;
    const int ko = (lane >> 4) * 8;
    #pragma unroll
    for (int nt = 0; nt < 2; ++nt) {
      const int row = wid * 512 + jbase + nt * 16 + rr;
      #pragma unroll
      for (int kt = 0; kt < 16; ++kt) {
        bih[nt][kt] = *(const short8v*)(wih + (size_t)row * 512 + kt * 32 + ko);
        bhh[nt][kt] = *(const short8v*)(whh + (size_t)row * 512 + kt * 32 + ko);
      }
    }
  }

  // gate-phase ownership: thread -> (b, jj)
  const int cb = tid >> 5;
  const int cj = tid & 31;
  float c_state = 0.f;
  const float bz0 = bias[0 * 512 + jbase + cj];
  const float bz1 = bias[1 * 512 + jbase + cj];
  const float bz2 = bias[2 * 512 + jbase + cj];
  const float bz3 = bias[3 * 512 + jbase + cj];

  // A-fragment: row = lane&7 (lanes 8..15 duplicate rows 0..7; their D rows
  // are never stored), k = (lane>>4)*8
  const int rowc = lane & 7;
  const int ako  = (lane >> 4) * 8;

  const f32x4 fzero = {0.f, 0.f, 0.f, 0.f};
  f32x4 acc0 = fzero, acc1 = fzero;

  // x-projection for step 0 (no h dependency); x read f32 from d_in
  {
    const int t0 = dir ? 1023 : 0;
    const float* xr = xf + ((size_t)rowc * 1024 + t0) * 512 + ako;
    #pragma unroll
    for (int kt = 0; kt < 16; ++kt) {
      short8v ax = cvtx8(xr + kt * 32);
      acc0 = __builtin_amdgcn_mfma_f32_16x16x32_bf16(ax, bih[0][kt], acc0, 0, 0, 0);
      acc1 = __builtin_amdgcn_mfma_f32_16x16x32_bf16(ax, bih[1][kt], acc1, 0, 0, 0);
    }
  }

  for (int step = 0; step < 1024; ++step) {
    if (step > 0) {
      // RELAXED poll: agent-scope atomic loads are serviced at the LLC
      // (coherence point) each iteration — observes remote publishes without
      // issuing any cache-invalidate. Bounded: broken handoff => wrong
      // answer, not a watchdog abort.
      if (tid < 16) {
        int guard = 0;
        while (__hip_atomic_load(&fl[tid], __ATOMIC_RELAXED, __HIP_MEMORY_SCOPE_AGENT)
               < (uint32_t)step && ++guard < (1 << 15)) { }
      }
      __syncthreads();
      // ONE acquire fence for the step: invalidate stale L1/L2 h lines.
      __builtin_amdgcn_fence(__ATOMIC_ACQUIRE, "agent");
      // h-part MFMAs (critical path)
      const u16* hr = hsb + ((size_t)step * 8 + rowc) * 512 + ako;
      #pragma unroll
      for (int kt = 0; kt < 16; ++kt) {
        short8v ah = *(const short8v*)(hr + kt * 32);
        acc0 = __builtin_amdgcn_mfma_f32_16x16x32_bf16(ah, bhh[0][kt], acc0, 0, 0, 0);
        acc1 = __builtin_amdgcn_mfma_f32_16x16x32_bf16(ah, bhh[1][kt], acc1, 0, 0, 0);
      }
    }
    // route z to LDS: D row m=(lane>>4)*4+r (rows<8 live in lanes<32), col=lane&15
    if (lane < 32) {
      #pragma unroll
      for (int r = 0; r < 4; ++r) {
        const int brow = (lane >> 4) * 4 + r;
        zL[wid * 256 + brow * 32 + (lane & 15)]      = acc0[r];
        zL[wid * 256 + brow * 32 + 16 + (lane & 15)] = acc1[r];
      }
    }
    __syncthreads();
    // gate math, one (b,jj) per thread; c stays in a register
    {
      float zi = zL[0 * 256 + cb * 32 + cj] + bz0;
      float zf = zL[1 * 256 + cb * 32 + cj] + bz1;
      float zg = zL[2 * 256 + cb * 32 + cj] + bz2;
      float zo = zL[3 * 256 + cb * 32 + cj] + bz3;
      float si = 1.f / (1.f + __expf(-zi));
      float sf = 1.f / (1.f + __expf(-zf));
      float so = 1.f / (1.f + __expf(-zo));
      float ag = fabsf(zg); float eg = __expf(-2.f * ag);
      float tg = (1.f - eg) / (1.f + eg); tg = copysignf(tg, zg);
      c_state = sf * c_state + si * tg;
      float ac = fabsf(c_state); float ec = __expf(-2.f * ac);
      float tc = (1.f - ec) / (1.f + ec); tc = copysignf(tc, c_state);
      float h = so * tc;
      hsb[((size_t)(step + 1) * 8 + cb) * 512 + jbase + cj] = f2bf(h);
      if (step == 1023) {
        out[OUT_HN + dir * 4096 + cb * 512 + jbase + cj] = h;
        out[OUT_CN + dir * 4096 + cb * 512 + jbase + cj] = c_state;
      }
    }
    __syncthreads();  // implies vmcnt(0): this WG's h stores are in L2
    if (tid == 0) {
      // release RMW: wbl2 (h col -> LLC) then add at the coherence point
      __hip_atomic_fetch_add(&fl[wg], 1u, __ATOMIC_RELEASE, __HIP_MEMORY_SCOPE_AGENT);
    }
    // x-projection for next step — off the critical path (after publish)
    if (step < 1023) {
      acc0 = fzero; acc1 = fzero;
      const int tn = dir ? (1022 - step) : (step + 1);
      const float* xr = xf + ((size_t)rowc * 1024 + tn) * 512 + ako;
      #pragma unroll
      for (int kt = 0; kt < 16; ++kt) {
        short8v ax = cvtx8(xr + kt * 32);
        acc0 = __builtin_amdgcn_mfma_f32_16x16x32_bf16(ax, bih[0][kt], acc0, 0, 0, 0);
        acc1 = __builtin_amdgcn_mfma_f32_16x16x32_bf16(ax, bih[1][kt], acc1, 0, 0, 0);
      }
    }
  }
}

// Neighbor-average epilogue — R9/R10-proven (order is int32 on device).
// One block per (b, s), s in [1,1022].
// padded[b][t][c]: c<512 -> hsb0 col t+1 ; c>=512 -> hsb1 col 1024-t.
__global__ void k_combine(const u16* __restrict__ hsb0, const u16* __restrict__ hsb1,
                          const int* __restrict__ cidx, const int* __restrict__ cmask,
                          const int* __restrict__ order, float* __restrict__ out)
{
  const int tid = threadIdx.x;
  const int b = blockIdx.x / 1022;
  const int s = 1 + (blockIdx.x % 1022);
  __shared__ int sidx[8];
  __shared__ float smask[8];
  __shared__ int rsh;
  if (tid == 0) rsh = order[b];
  __syncthreads();
  const int r = rsh;
  if (tid < 8) {
    size_t base = ((size_t)r * 1024 + s) * 8 + tid;
    sidx[tid] = cidx[base];
    smask[tid] = (float)cmask[base];
  }
  __syncthreads();
  float cnt = 0.f;
  #pragma unroll
  for (int k = 0; k < 8; ++k) cnt += smask[k];
  const float inv = 1.f / (1.f + cnt);

  const int col0 = tid * 4;
  const bool isF = col0 < 512;
  const int cloc = isF ? col0 : col0 - 512;
  const u16* hb = isF ? hsb0 : hsb1;

  float v0, v1, v2, v3;
  {
    size_t ci2 = isF ? (size_t)(s + 1) : (size_t)(1024 - s);
    ushort4 q = *(const ushort4*)(hb + (ci2 * 8 + b) * 512 + cloc);
    v0 = bf2f(q.x); v1 = bf2f(q.y); v2 = bf2f(q.z); v3 = bf2f(q.w);
  }
  #pragma unroll
  for (int k = 0; k < 8; ++k) {
    float m = smask[k];
    if (m != 0.f) {
      int sp = sidx[k];
      size_t ci2 = isF ? (size_t)(sp + 1) : (size_t)(1024 - sp);
      ushort4 q = *(const ushort4*)(hb + (ci2 * 8 + b) * 512 + cloc);
      v0 += m * bf2f(q.x); v1 += m * bf2f(q.y); v2 += m * bf2f(q.z); v3 += m * bf2f(q.w);
    }
  }
  size_t ob = ((size_t)r * 1022 + (s - 1)) * 1024 + col0;
  float4 ov; ov.x = v0 * inv; ov.y = v1 * inv; ov.z = v2 * inv; ov.w = v3 * inv;
  *(float4*)(out + ob) = ov;
}

extern "C" void kernel_launch(void* const* d_in, const int* in_sizes, int n_in,
                              void* d_out, int out_size, void* d_ws, size_t ws_size,
                              hipStream_t stream)
{
  const float* x      = (const float*)d_in[0];
  const int*   cidx   = (const int*)d_in[1];
  const int*   cmask  = (const int*)d_in[2];
  const int*   order  = (const int*)d_in[3];   // int64 in reference -> int32 on device
  const float* wihf = (const float*)d_in[4];
  const float* whhf = (const float*)d_in[5];
  const float* bf   = (const float*)d_in[6];
  const float* wihb = (const float*)d_in[7];
  const float* whhb = (const float*)d_in[8];
  const float* bb   = (const float*)d_in[9];
  float* out = (float*)d_out;

  char* ws = (char*)d_ws;
  u16* WIH0 = (u16*)(ws + WS_WIH0);
  u16* WIH1 = (u16*)(ws + WS_WIH1);
  u16* WHH0 = (u16*)(ws + WS_WHH0);
  u16* WHH1 = (u16*)(ws + WS_WHH1);
  u16* HSB0 = (u16*)(ws + WS_HSB0);
  u16* HSB1 = (u16*)(ws + WS_HSB1);
  uint32_t* FLAGS = (uint32_t*)(ws + WS_FLAGS);

  hipLaunchKernelGGL(k_f2bf, dim3(256), dim3(256), 0, stream, wihf, WIH0, 2048 * 512);
  hipLaunchKernelGGL(k_f2bf, dim3(256), dim3(256), 0, stream, wihb, WIH1, 2048 * 512);
  hipLaunchKernelGGL(k_f2bf, dim3(256), dim3(256), 0, stream, whhf, WHH0, 2048 * 512);
  hipLaunchKernelGGL(k_f2bf, dim3(256), dim3(256), 0, stream, whhb, WHH1, 2048 * 512);
  hipLaunchKernelGGL(k_init, dim3(1), dim3(64), 0, stream, FLAGS);
  hipLaunchKernelGGL(k_lstm, dim3(32), dim3(256), 0, stream,
                     x, WIH0, WIH1, WHH0, WHH1, bf, bb, HSB0, HSB1, out, FLAGS);
  hipLaunchKernelGGL(k_combine, dim3(8 * 1022), dim3(256), 0, stream,
                     HSB0, HSB1, cidx, cmask, order, out);
}

// Round 12
// 4556.391 us; speedup vs baseline: 2.3943x; 2.3943x over previous
//
#include <hip/hip_runtime.h>
#include <stdint.h>

typedef unsigned short u16;
typedef __attribute__((ext_vector_type(8))) short short8v;
typedef __attribute__((ext_vector_type(4))) float f32x4;

// output layout (floats): out(8,1022,1024) | h_n(2,8,512) | c_n(2,8,512)
#define OUT_HN   8372224
#define OUT_CN   8380416

// ws layout (bytes) — total 25,182,464 B (R9-proven safe)
#define WS_WIH0  0
#define WS_WIH1  (WS_WIH0 + 2097152)
#define WS_WHH0  (WS_WIH1 + 2097152)
#define WS_WHH1  (WS_WHH0 + 2097152)
#define WS_HSB0  (WS_WHH1 + 2097152)        // 1025*8*512 bf16 = 8,396,800 B
#define WS_HSB1  (WS_HSB0 + 8396800)
#define WS_FLAGS (WS_HSB1 + 8396800)        // 64 * u32

__device__ __forceinline__ u16 f2bf(float f) {
  uint32_t u = __float_as_uint(f);
  u += 0x7FFFu + ((u >> 16) & 1u);
  return (u16)(u >> 16);
}
__device__ __forceinline__ float bf2f(u16 v) {
  return __uint_as_float(((uint32_t)v) << 16);
}

__global__ void k_f2bf(const float* __restrict__ src, u16* __restrict__ dst, int n) {
  int i = blockIdx.x * blockDim.x + threadIdx.x;
  int stride = gridDim.x * blockDim.x;
  for (; i < n; i += stride) dst[i] = f2bf(src[i]);
}

__global__ void k_init(uint32_t* flags) {
  if (threadIdx.x < 64) flags[threadIdx.x] = 0;
}

// Persistent bidirectional LSTM. grid = 32 blocks x 256 threads.
// blocks 0..15: forward, 16..31: backward. Each WG owns 32 hidden units.
// Wave w = gate w (i,f,g,o). W fragments live in per-thread arrays (AGPR-
// backed). R12 change: A-operands (h col, x col) are COOPERATIVELY staged
// into LDS (one parallel LLC round trip instead of 16 serialized per-kt
// global loads — R9..R11 all paid ~8us/step for that serialization).
// LDS tiles are XOR-block-swizzled: 16B block B of row r stored at B^r,
// capping ds_read_b128 conflicts at the 4-way pigeonhole minimum.
__launch_bounds__(256, 1)
__global__ void k_lstm(const float* __restrict__ xf,
                       const u16* __restrict__ wih0, const u16* __restrict__ wih1,
                       const u16* __restrict__ whh0, const u16* __restrict__ whh1,
                       const float* __restrict__ bias0, const float* __restrict__ bias1,
                       u16* hsb0, u16* hsb1, float* out, uint32_t* flags)
{
  const int tid  = threadIdx.x;
  const int wid  = tid >> 6;     // wave = gate
  const int lane = tid & 63;
  const int dir  = blockIdx.x >> 4;
  const int wg   = blockIdx.x & 15;
  const int jbase = wg * 32;

  const u16*  wih  = dir ? wih1  : wih0;
  const u16*  whh  = dir ? whh1  : whh0;
  const float* bias = dir ? bias1 : bias0;
  u16* hsb = dir ? hsb1 : hsb0;
  uint32_t* fl = flags + dir * 16;

  __shared__ u16 hL[8 * 512];        // swizzled h column tile (8 KB)
  __shared__ u16 xL[8 * 512];        // swizzled x column tile (8 KB)
  __shared__ float zL[4 * 8 * 32];   // [gate][b][jj]

  // B-fragments: lane holds W[row = g*512 + jbase + nt*16 + (lane&15)]
  //                          [k = kt*32 + (lane>>4)*8 .. +8]
  short8v bih[2][16], bhh[2][16];
  {
    const int rr = lane & 15;
    const int ko = (lane >> 4) * 8;
    #pragma unroll
    for (int nt = 0; nt < 2; ++nt) {
      const int row = wid * 512 + jbase + nt * 16 + rr;
      #pragma unroll
      for (int kt = 0; kt < 16; ++kt) {
        bih[nt][kt] = *(const short8v*)(wih + (size_t)row * 512 + kt * 32 + ko);
        bhh[nt][kt] = *(const short8v*)(whh + (size_t)row * 512 + kt * 32 + ko);
      }
    }
  }

  // gate-phase ownership: thread -> (b, jj)
  const int cb = tid >> 5;
  const int cj = tid & 31;
  float c_state = 0.f;
  const float bz0 = bias[0 * 512 + jbase + cj];
  const float bz1 = bias[1 * 512 + jbase + cj];
  const float bz2 = bias[2 * 512 + jbase + cj];
  const float bz3 = bias[3 * 512 + jbase + cj];

  // A-fragment lane mapping: row = lane&7 (lanes 8..15 duplicate; their D
  // rows never stored), q = lane>>4 selects the 8-elem k-slot
  const int rB = lane & 7;
  const int q  = lane >> 4;

  const f32x4 fzero = {0.f, 0.f, 0.f, 0.f};
  f32x4 acc0 = fzero, acc1 = fzero;

  // ---- stage x col t into swizzled xL: thread handles 16B blocks g, g+256
  #define STAGE_X(tcol)                                                        \
    {                                                                          \
      _Pragma("unroll")                                                        \
      for (int half = 0; half < 2; ++half) {                                   \
        int g = tid + half * 256;                                              \
        int r = g >> 6, B = g & 63;                                            \
        const float* xr = xf + ((size_t)r * 1024 + (tcol)) * 512 + B * 8;      \
        float4 a = *(const float4*)xr;                                         \
        float4 b = *(const float4*)(xr + 4);                                   \
        short8v v;                                                             \
        v[0] = (short)f2bf(a.x); v[1] = (short)f2bf(a.y);                      \
        v[2] = (short)f2bf(a.z); v[3] = (short)f2bf(a.w);                      \
        v[4] = (short)f2bf(b.x); v[5] = (short)f2bf(b.y);                      \
        v[6] = (short)f2bf(b.z); v[7] = (short)f2bf(b.w);                      \
        *(short8v*)(xL + r * 512 + ((B ^ r) << 3)) = v;                        \
      }                                                                        \
    }

  // prologue: x-projection for step 0
  {
    const int t0 = dir ? 1023 : 0;
    STAGE_X(t0);
    __syncthreads();
    #pragma unroll
    for (int kt = 0; kt < 16; ++kt) {
      short8v ax = *(const short8v*)(xL + rB * 512 + (((kt * 4 + q) ^ rB) << 3));
      acc0 = __builtin_amdgcn_mfma_f32_16x16x32_bf16(ax, bih[0][kt], acc0, 0, 0, 0);
      acc1 = __builtin_amdgcn_mfma_f32_16x16x32_bf16(ax, bih[1][kt], acc1, 0, 0, 0);
    }
  }

  for (int step = 0; step < 1024; ++step) {
    if (step > 0) {
      // relaxed agent poll (LLC-serviced); bounded so a broken handoff is a
      // wrong answer, not a watchdog abort
      if (tid < 16) {
        int guard = 0;
        while (__hip_atomic_load(&fl[tid], __ATOMIC_RELAXED, __HIP_MEMORY_SCOPE_AGENT)
               < (uint32_t)step && ++guard < (1 << 15)) { }
      }
      __syncthreads();
      __builtin_amdgcn_fence(__ATOMIC_ACQUIRE, "agent");
      // cooperative h-column stage: one parallel LLC round trip
      {
        const u16* hc = hsb + (size_t)step * 4096;
        short8v v0 = *(const short8v*)(hc + tid * 8);
        short8v v1 = *(const short8v*)(hc + 2048 + tid * 8);
        int r0 = tid >> 6, B0 = tid & 63;
        int r1 = r0 + 4;
        *(short8v*)(hL + r0 * 512 + ((B0 ^ r0) << 3)) = v0;
        *(short8v*)(hL + r1 * 512 + ((B0 ^ r1) << 3)) = v1;
      }
      __syncthreads();
      // h-projection from LDS (critical path)
      #pragma unroll
      for (int kt = 0; kt < 16; ++kt) {
        short8v ah = *(const short8v*)(hL + rB * 512 + (((kt * 4 + q) ^ rB) << 3));
        acc0 = __builtin_amdgcn_mfma_f32_16x16x32_bf16(ah, bhh[0][kt], acc0, 0, 0, 0);
        acc1 = __builtin_amdgcn_mfma_f32_16x16x32_bf16(ah, bhh[1][kt], acc1, 0, 0, 0);
      }
    }
    // route z to LDS: D row m=(lane>>4)*4+r (rows<8 live in lanes<32), col=lane&15
    if (lane < 32) {
      #pragma unroll
      for (int r = 0; r < 4; ++r) {
        const int brow = (lane >> 4) * 4 + r;
        zL[wid * 256 + brow * 32 + (lane & 15)]      = acc0[r];
        zL[wid * 256 + brow * 32 + 16 + (lane & 15)] = acc1[r];
      }
    }
    __syncthreads();
    // gate math, one (b,jj) per thread; c stays in a register
    {
      float zi = zL[0 * 256 + cb * 32 + cj] + bz0;
      float zf = zL[1 * 256 + cb * 32 + cj] + bz1;
      float zg = zL[2 * 256 + cb * 32 + cj] + bz2;
      float zo = zL[3 * 256 + cb * 32 + cj] + bz3;
      float si = 1.f / (1.f + __expf(-zi));
      float sf = 1.f / (1.f + __expf(-zf));
      float so = 1.f / (1.f + __expf(-zo));
      float ag = fabsf(zg); float eg = __expf(-2.f * ag);
      float tg = (1.f - eg) / (1.f + eg); tg = copysignf(tg, zg);
      c_state = sf * c_state + si * tg;
      float ac = fabsf(c_state); float ec = __expf(-2.f * ac);
      float tc = (1.f - ec) / (1.f + ec); tc = copysignf(tc, c_state);
      float h = so * tc;
      hsb[((size_t)(step + 1) * 8 + cb) * 512 + jbase + cj] = f2bf(h);
      if (step == 1023) {
        out[OUT_HN + dir * 4096 + cb * 512 + jbase + cj] = h;
        out[OUT_CN + dir * 4096 + cb * 512 + jbase + cj] = c_state;
      }
    }
    __syncthreads();  // vmcnt(0): all lanes' h stores in L2 before publish
    if (tid == 0) {
      // release RMW: wbl2 (h col -> LLC) then add at the coherence point
      __hip_atomic_fetch_add(&fl[wg], 1u, __ATOMIC_RELEASE, __HIP_MEMORY_SCOPE_AGENT);
    }
    // x stage + projection for next step — parallel phase (after publish)
    if (step < 1023) {
      acc0 = fzero; acc1 = fzero;
      const int tn = dir ? (1022 - step) : (step + 1);
      STAGE_X(tn);
      __syncthreads();
      #pragma unroll
      for (int kt = 0; kt < 16; ++kt) {
        short8v ax = *(const short8v*)(xL + rB * 512 + (((kt * 4 + q) ^ rB) << 3));
        acc0 = __builtin_amdgcn_mfma_f32_16x16x32_bf16(ax, bih[0][kt], acc0, 0, 0, 0);
        acc1 = __builtin_amdgcn_mfma_f32_16x16x32_bf16(ax, bih[1][kt], acc1, 0, 0, 0);
      }
    }
  }
}

// Neighbor-average epilogue — R9-proven (order is int32 on device).
// One block per (b, s), s in [1,1022].
// padded[b][t][c]: c<512 -> hsb0 col t+1 ; c>=512 -> hsb1 col 1024-t.
__global__ void k_combine(const u16* __restrict__ hsb0, const u16* __restrict__ hsb1,
                          const int* __restrict__ cidx, const int* __restrict__ cmask,
                          const int* __restrict__ order, float* __restrict__ out)
{
  const int tid = threadIdx.x;
  const int b = blockIdx.x / 1022;
  const int s = 1 + (blockIdx.x % 1022);
  __shared__ int sidx[8];
  __shared__ float smask[8];
  __shared__ int rsh;
  if (tid == 0) rsh = order[b];
  __syncthreads();
  const int r = rsh;
  if (tid < 8) {
    size_t base = ((size_t)r * 1024 + s) * 8 + tid;
    sidx[tid] = cidx[base];
    smask[tid] = (float)cmask[base];
  }
  __syncthreads();
  float cnt = 0.f;
  #pragma unroll
  for (int k = 0; k < 8; ++k) cnt += smask[k];
  const float inv = 1.f / (1.f + cnt);

  const int col0 = tid * 4;
  const bool isF = col0 < 512;
  const int cloc = isF ? col0 : col0 - 512;
  const u16* hb = isF ? hsb0 : hsb1;

  float v0, v1, v2, v3;
  {
    size_t ci2 = isF ? (size_t)(s + 1) : (size_t)(1024 - s);
    ushort4 qv = *(const ushort4*)(hb + (ci2 * 8 + b) * 512 + cloc);
    v0 = bf2f(qv.x); v1 = bf2f(qv.y); v2 = bf2f(qv.z); v3 = bf2f(qv.w);
  }
  #pragma unroll
  for (int k = 0; k < 8; ++k) {
    float m = smask[k];
    if (m != 0.f) {
      int sp = sidx[k];
      size_t ci2 = isF ? (size_t)(sp + 1) : (size_t)(1024 - sp);
      ushort4 qv = *(const ushort4*)(hb + (ci2 * 8 + b) * 512 + cloc);
      v0 += m * bf2f(qv.x); v1 += m * bf2f(qv.y); v2 += m * bf2f(qv.z); v3 += m * bf2f(qv.w);
    }
  }
  size_t ob = ((size_t)r * 1022 + (s - 1)) * 1024 + col0;
  float4 ov; ov.x = v0 * inv; ov.y = v1 * inv; ov.z = v2 * inv; ov.w = v3 * inv;
  *(float4*)(out + ob) = ov;
}

extern "C" void kernel_launch(void* const* d_in, const int* in_sizes, int n_in,
                              void* d_out, int out_size, void* d_ws, size_t ws_size,
                              hipStream_t stream)
{
  const float* x      = (const float*)d_in[0];
  const int*   cidx   = (const int*)d_in[1];
  const int*   cmask  = (const int*)d_in[2];
  const int*   order  = (const int*)d_in[3];   // int64 in reference -> int32 on device
  const float* wihf = (const float*)d_in[4];
  const float* whhf = (const float*)d_in[5];
  const float* bf   = (const float*)d_in[6];
  const float* wihb = (const float*)d_in[7];
  const float* whhb = (const float*)d_in[8];
  const float* bb   = (const float*)d_in[9];
  float* out = (float*)d_out;

  char* ws = (char*)d_ws;
  u16* WIH0 = (u16*)(ws + WS_WIH0);
  u16* WIH1 = (u16*)(ws + WS_WIH1);
  u16* WHH0 = (u16*)(ws + WS_WHH0);
  u16* WHH1 = (u16*)(ws + WS_WHH1);
  u16* HSB0 = (u16*)(ws + WS_HSB0);
  u16* HSB1 = (u16*)(ws + WS_HSB1);
  uint32_t* FLAGS = (uint32_t*)(ws + WS_FLAGS);

  hipLaunchKernelGGL(k_f2bf, dim3(256), dim3(256), 0, stream, wihf, WIH0, 2048 * 512);
  hipLaunchKernelGGL(k_f2bf, dim3(256), dim3(256), 0, stream, wihb, WIH1, 2048 * 512);
  hipLaunchKernelGGL(k_f2bf, dim3(256), dim3(256), 0, stream, whhf, WHH0, 2048 * 512);
  hipLaunchKernelGGL(k_f2bf, dim3(256), dim3(256), 0, stream, whhb, WHH1, 2048 * 512);
  hipLaunchKernelGGL(k_init, dim3(1), dim3(64), 0, stream, FLAGS);
  hipLaunchKernelGGL(k_lstm, dim3(32), dim3(256), 0, stream,
                     x, WIH0, WIH1, WHH0, WHH1, bf, bb, HSB0, HSB1, out, FLAGS);
  hipLaunchKernelGGL(k_combine, dim3(8 * 1022), dim3(256), 0, stream,
                     HSB0, HSB1, cidx, cmask, order, out);
}

// Round 13
// 3352.523 us; speedup vs baseline: 3.2541x; 1.3591x over previous
//
#include <hip/hip_runtime.h>
#include <stdint.h>

typedef unsigned short u16;
typedef unsigned long long u64;
typedef __attribute__((ext_vector_type(8))) short short8v;
typedef __attribute__((ext_vector_type(4))) float f32x4;

// output layout (floats): out(8,1022,1024) | h_n(2,8,512) | c_n(2,8,512)
#define OUT_HN   8372224
#define OUT_CN   8380416

// ws layout (bytes)
#define WS_WIH0  0
#define WS_WIH1  (WS_WIH0 + 2097152)
#define WS_WHH0  (WS_WIH1 + 2097152)
#define WS_WHH1  (WS_WHH0 + 2097152)
#define WS_HSB0  (WS_WHH1 + 2097152)        // 1025*8*512 bf16 = 8,396,800 B
#define WS_HSB1  (WS_HSB0 + 8396800)
#define WS_FLAGS (WS_HSB1 + 8396800)        // 64 * u32

__device__ __forceinline__ u16 f2bf(float f) {
  uint32_t u = __float_as_uint(f);
  u += 0x7FFFu + ((u >> 16) & 1u);
  return (u16)(u >> 16);
}
__device__ __forceinline__ float bf2f(u16 v) {
  return __uint_as_float(((uint32_t)v) << 16);
}

__global__ void k_f2bf(const float* __restrict__ src, u16* __restrict__ dst, int n) {
  int i = blockIdx.x * blockDim.x + threadIdx.x;
  int stride = gridDim.x * blockDim.x;
  for (; i < n; i += stride) dst[i] = f2bf(src[i]);
}

__global__ void k_init(uint32_t* flags) {
  if (threadIdx.x < 64) flags[threadIdx.x] = 0;
}

// Persistent bidirectional LSTM. grid = 32 blocks x 256 threads.
// blocks 0..15: forward, 16..31: backward. Each WG owns 32 hidden units.
// Wave w = gate w. W fragments resident in VGPRs.
// R13 protocol — FENCE-FREE handoff: h columns move exclusively via
// agent-scope relaxed ATOMIC u64 loads/stores (serviced at the LLC, bypass
// L1/L2 both ways). Writer: pack h slice in LDS -> wave0 stores 64 u64
// atomics -> s_waitcnt vmcnt(0) (same-wave: data at coherence point) ->
// relaxed flag store. Reader: relaxed flag poll -> bulk atomic column load.
// NO acquire/release fences in the loop => L2 stays warm (R12 paid 193MB
// refetch + serial buffer_inv/wbl2 per step for them).
__launch_bounds__(256, 1)
__global__ void k_lstm(const float* __restrict__ xf,
                       const u16* __restrict__ wih0, const u16* __restrict__ wih1,
                       const u16* __restrict__ whh0, const u16* __restrict__ whh1,
                       const float* __restrict__ bias0, const float* __restrict__ bias1,
                       u16* hsb0, u16* hsb1, float* out, uint32_t* flags)
{
  const int tid  = threadIdx.x;
  const int wid  = tid >> 6;     // wave = gate
  const int lane = tid & 63;
  const int dir  = blockIdx.x >> 4;
  const int wg   = blockIdx.x & 15;
  const int jbase = wg * 32;

  const u16*  wih  = dir ? wih1  : wih0;
  const u16*  whh  = dir ? whh1  : whh0;
  const float* bias = dir ? bias1 : bias0;
  u16* hsb = dir ? hsb1 : hsb0;
  uint32_t* fl = flags + dir * 16;

  __shared__ u16 hL[8 * 512];        // swizzled h column tile (8 KB)
  __shared__ u16 xL[8 * 512];        // swizzled x column tile (8 KB)
  __shared__ float zL[4 * 8 * 32];   // [gate][b][jj]
  __shared__ u16 hS[8 * 32];         // this WG's h slice (b-major)

  // B-fragments: lane holds W[row = g*512 + jbase + nt*16 + (lane&15)]
  //                          [k = kt*32 + (lane>>4)*8 .. +8]
  short8v bih[2][16], bhh[2][16];
  {
    const int rr = lane & 15;
    const int ko = (lane >> 4) * 8;
    #pragma unroll
    for (int nt = 0; nt < 2; ++nt) {
      const int row = wid * 512 + jbase + nt * 16 + rr;
      #pragma unroll
      for (int kt = 0; kt < 16; ++kt) {
        bih[nt][kt] = *(const short8v*)(wih + (size_t)row * 512 + kt * 32 + ko);
        bhh[nt][kt] = *(const short8v*)(whh + (size_t)row * 512 + kt * 32 + ko);
      }
    }
  }

  // gate-phase ownership: thread -> (b, jj)
  const int cb = tid >> 5;
  const int cj = tid & 31;
  float c_state = 0.f;
  const float bz0 = bias[0 * 512 + jbase + cj];
  const float bz1 = bias[1 * 512 + jbase + cj];
  const float bz2 = bias[2 * 512 + jbase + cj];
  const float bz3 = bias[3 * 512 + jbase + cj];

  // A-fragment lane mapping
  const int rB = lane & 7;
  const int q  = lane >> 4;

  const f32x4 fzero = {0.f, 0.f, 0.f, 0.f};
  f32x4 acc0 = fzero, acc1 = fzero;

  // stage x col t into swizzled xL (plain loads — x is read-only, L2-warm)
  #define STAGE_X(tcol)                                                        \
    {                                                                          \
      _Pragma("unroll")                                                        \
      for (int half = 0; half < 2; ++half) {                                   \
        int g = tid + half * 256;                                              \
        int r = g >> 6, B = g & 63;                                            \
        const float* xr = xf + ((size_t)r * 1024 + (tcol)) * 512 + B * 8;      \
        float4 a = *(const float4*)xr;                                         \
        float4 b = *(const float4*)(xr + 4);                                   \
        short8v v;                                                             \
        v[0] = (short)f2bf(a.x); v[1] = (short)f2bf(a.y);                      \
        v[2] = (short)f2bf(a.z); v[3] = (short)f2bf(a.w);                      \
        v[4] = (short)f2bf(b.x); v[5] = (short)f2bf(b.y);                      \
        v[6] = (short)f2bf(b.z); v[7] = (short)f2bf(b.w);                      \
        *(short8v*)(xL + r * 512 + ((B ^ r) << 3)) = v;                        \
      }                                                                        \
    }

  // prologue: x-projection for step 0
  {
    const int t0 = dir ? 1023 : 0;
    STAGE_X(t0);
    __syncthreads();
    #pragma unroll
    for (int kt = 0; kt < 16; ++kt) {
      short8v ax = *(const short8v*)(xL + rB * 512 + (((kt * 4 + q) ^ rB) << 3));
      acc0 = __builtin_amdgcn_mfma_f32_16x16x32_bf16(ax, bih[0][kt], acc0, 0, 0, 0);
      acc1 = __builtin_amdgcn_mfma_f32_16x16x32_bf16(ax, bih[1][kt], acc1, 0, 0, 0);
    }
  }

  for (int step = 0; step < 1024; ++step) {
    if (step > 0) {
      // relaxed agent poll (LLC-serviced); bounded (broken handoff => wrong
      // answer, not watchdog abort)
      if (tid < 16) {
        int guard = 0;
        while (__hip_atomic_load(&fl[tid], __ATOMIC_RELAXED, __HIP_MEMORY_SCOPE_AGENT)
               < (uint32_t)step && ++guard < (1 << 15)) { }
      }
      __syncthreads();
      // bulk h-column load via relaxed atomic u64 (LLC-fresh, no fence),
      // scatter into swizzled hL
      {
        const u64* hc = (const u64*)(hsb + (size_t)step * 4096);
        u64 d0 = __hip_atomic_load(hc + 4 * tid + 0, __ATOMIC_RELAXED, __HIP_MEMORY_SCOPE_AGENT);
        u64 d1 = __hip_atomic_load(hc + 4 * tid + 1, __ATOMIC_RELAXED, __HIP_MEMORY_SCOPE_AGENT);
        u64 d2 = __hip_atomic_load(hc + 4 * tid + 2, __ATOMIC_RELAXED, __HIP_MEMORY_SCOPE_AGENT);
        u64 d3 = __hip_atomic_load(hc + 4 * tid + 3, __ATOMIC_RELAXED, __HIP_MEMORY_SCOPE_AGENT);
        union { u64 qq[2]; short8v v; } p0, p1;
        p0.qq[0] = d0; p0.qq[1] = d1;
        p1.qq[0] = d2; p1.qq[1] = d3;
        int G0 = 2 * tid, G1 = 2 * tid + 1;
        int r0 = G0 >> 6, B0 = G0 & 63;
        int r1 = G1 >> 6, B1 = G1 & 63;
        *(short8v*)(hL + r0 * 512 + ((B0 ^ r0) << 3)) = p0.v;
        *(short8v*)(hL + r1 * 512 + ((B1 ^ r1) << 3)) = p1.v;
      }
      __syncthreads();
      // h-projection from LDS (critical path)
      #pragma unroll
      for (int kt = 0; kt < 16; ++kt) {
        short8v ah = *(const short8v*)(hL + rB * 512 + (((kt * 4 + q) ^ rB) << 3));
        acc0 = __builtin_amdgcn_mfma_f32_16x16x32_bf16(ah, bhh[0][kt], acc0, 0, 0, 0);
        acc1 = __builtin_amdgcn_mfma_f32_16x16x32_bf16(ah, bhh[1][kt], acc1, 0, 0, 0);
      }
    }
    // route z to LDS
    if (lane < 32) {
      #pragma unroll
      for (int r = 0; r < 4; ++r) {
        const int brow = (lane >> 4) * 4 + r;
        zL[wid * 256 + brow * 32 + (lane & 15)]      = acc0[r];
        zL[wid * 256 + brow * 32 + 16 + (lane & 15)] = acc1[r];
      }
    }
    __syncthreads();
    // gate math; h slice to hS (LDS)
    {
      float zi = zL[0 * 256 + cb * 32 + cj] + bz0;
      float zf = zL[1 * 256 + cb * 32 + cj] + bz1;
      float zg = zL[2 * 256 + cb * 32 + cj] + bz2;
      float zo = zL[3 * 256 + cb * 32 + cj] + bz3;
      float si = 1.f / (1.f + __expf(-zi));
      float sf = 1.f / (1.f + __expf(-zf));
      float so = 1.f / (1.f + __expf(-zo));
      float ag = fabsf(zg); float eg = __expf(-2.f * ag);
      float tg = (1.f - eg) / (1.f + eg); tg = copysignf(tg, zg);
      c_state = sf * c_state + si * tg;
      float ac = fabsf(c_state); float ec = __expf(-2.f * ac);
      float tc = (1.f - ec) / (1.f + ec); tc = copysignf(tc, c_state);
      float h = so * tc;
      hS[cb * 32 + cj] = f2bf(h);
      if (step == 1023) {
        out[OUT_HN + dir * 4096 + cb * 512 + jbase + cj] = h;
        out[OUT_CN + dir * 4096 + cb * 512 + jbase + cj] = c_state;
      }
    }
    __syncthreads();
    // wave 0: publish h slice as write-through atomics, then flag
    if (tid < 64) {
      const int pb = tid >> 3;         // batch
      const int pt = tid & 7;          // quad within 32 units
      u64 hv = *(const u64*)(hS + pb * 32 + 4 * pt);
      u64* dst = (u64*)(hsb + ((size_t)(step + 1) * 8 + pb) * 512 + jbase + 4 * pt);
      __hip_atomic_store(dst, hv, __ATOMIC_RELAXED, __HIP_MEMORY_SCOPE_AGENT);
      asm volatile("s_waitcnt vmcnt(0)" ::: "memory");  // slice at LLC
    }
    if (tid == 0) {
      __hip_atomic_store(&fl[wg], (uint32_t)(step + 1), __ATOMIC_RELAXED,
                         __HIP_MEMORY_SCOPE_AGENT);
    }
    // x stage + projection for next step (parallel phase)
    if (step < 1023) {
      acc0 = fzero; acc1 = fzero;
      const int tn = dir ? (1022 - step) : (step + 1);
      STAGE_X(tn);
      __syncthreads();
      #pragma unroll
      for (int kt = 0; kt < 16; ++kt) {
        short8v ax = *(const short8v*)(xL + rB * 512 + (((kt * 4 + q) ^ rB) << 3));
        acc0 = __builtin_amdgcn_mfma_f32_16x16x32_bf16(ax, bih[0][kt], acc0, 0, 0, 0);
        acc1 = __builtin_amdgcn_mfma_f32_16x16x32_bf16(ax, bih[1][kt], acc1, 0, 0, 0);
      }
    }
  }
}

// Neighbor-average epilogue — R9-proven (order is int32 on device).
__global__ void k_combine(const u16* __restrict__ hsb0, const u16* __restrict__ hsb1,
                          const int* __restrict__ cidx, const int* __restrict__ cmask,
                          const int* __restrict__ order, float* __restrict__ out)
{
  const int tid = threadIdx.x;
  const int b = blockIdx.x / 1022;
  const int s = 1 + (blockIdx.x % 1022);
  __shared__ int sidx[8];
  __shared__ float smask[8];
  __shared__ int rsh;
  if (tid == 0) rsh = order[b];
  __syncthreads();
  const int r = rsh;
  if (tid < 8) {
    size_t base = ((size_t)r * 1024 + s) * 8 + tid;
    sidx[tid] = cidx[base];
    smask[tid] = (float)cmask[base];
  }
  __syncthreads();
  float cnt = 0.f;
  #pragma unroll
  for (int k = 0; k < 8; ++k) cnt += smask[k];
  const float inv = 1.f / (1.f + cnt);

  const int col0 = tid * 4;
  const bool isF = col0 < 512;
  const int cloc = isF ? col0 : col0 - 512;
  const u16* hb = isF ? hsb0 : hsb1;

  float v0, v1, v2, v3;
  {
    size_t ci2 = isF ? (size_t)(s + 1) : (size_t)(1024 - s);
    ushort4 qv = *(const ushort4*)(hb + (ci2 * 8 + b) * 512 + cloc);
    v0 = bf2f(qv.x); v1 = bf2f(qv.y); v2 = bf2f(qv.z); v3 = bf2f(qv.w);
  }
  #pragma unroll
  for (int k = 0; k < 8; ++k) {
    float m = smask[k];
    if (m != 0.f) {
      int sp = sidx[k];
      size_t ci2 = isF ? (size_t)(sp + 1) : (size_t)(1024 - sp);
      ushort4 qv = *(const ushort4*)(hb + (ci2 * 8 + b) * 512 + cloc);
      v0 += m * bf2f(qv.x); v1 += m * bf2f(qv.y); v2 += m * bf2f(qv.z); v3 += m * bf2f(qv.w);
    }
  }
  size_t ob = ((size_t)r * 1022 + (s - 1)) * 1024 + col0;
  float4 ov; ov.x = v0 * inv; ov.y = v1 * inv; ov.z = v2 * inv; ov.w = v3 * inv;
  *(float4*)(out + ob) = ov;
}

extern "C" void kernel_launch(void* const* d_in, const int* in_sizes, int n_in,
                              void* d_out, int out_size, void* d_ws, size_t ws_size,
                              hipStream_t stream)
{
  const float* x      = (const float*)d_in[0];
  const int*   cidx   = (const int*)d_in[1];
  const int*   cmask  = (const int*)d_in[2];
  const int*   order  = (const int*)d_in[3];   // int64 in reference -> int32 on device
  const float* wihf = (const float*)d_in[4];
  const float* whhf = (const float*)d_in[5];
  const float* bf   = (const float*)d_in[6];
  const float* wihb = (const float*)d_in[7];
  const float* whhb = (const float*)d_in[8];
  const float* bb   = (const float*)d_in[9];
  float* out = (float*)d_out;

  char* ws = (char*)d_ws;
  u16* WIH0 = (u16*)(ws + WS_WIH0);
  u16* WIH1 = (u16*)(ws + WS_WIH1);
  u16* WHH0 = (u16*)(ws + WS_WHH0);
  u16* WHH1 = (u16*)(ws + WS_WHH1);
  u16* HSB0 = (u16*)(ws + WS_HSB0);
  u16* HSB1 = (u16*)(ws + WS_HSB1);
  uint32_t* FLAGS = (uint32_t*)(ws + WS_FLAGS);

  hipLaunchKernelGGL(k_f2bf, dim3(256), dim3(256), 0, stream, wihf, WIH0, 2048 * 512);
  hipLaunchKernelGGL(k_f2bf, dim3(256), dim3(256), 0, stream, wihb, WIH1, 2048 * 512);
  hipLaunchKernelGGL(k_f2bf, dim3(256), dim3(256), 0, stream, whhf, WHH0, 2048 * 512);
  hipLaunchKernelGGL(k_f2bf, dim3(256), dim3(256), 0, stream, whhb, WHH1, 2048 * 512);
  hipLaunchKernelGGL(k_init, dim3(1), dim3(64), 0, stream, FLAGS);
  hipLaunchKernelGGL(k_lstm, dim3(32), dim3(256), 0, stream,
                     x, WIH0, WIH1, WHH0, WHH1, bf, bb, HSB0, HSB1, out, FLAGS);
  hipLaunchKernelGGL(k_combine, dim3(8 * 1022), dim3(256), 0, stream,
                     HSB0, HSB1, cidx, cmask, order, out);
}

// Round 14
// 2973.774 us; speedup vs baseline: 3.6686x; 1.1274x over previous
//
#include <hip/hip_runtime.h>
#include <stdint.h>

typedef unsigned short u16;
typedef unsigned long long u64;
typedef __attribute__((ext_vector_type(8))) short short8v;
typedef __attribute__((ext_vector_type(4))) float f32x4;

// output layout (floats): out(8,1022,1024) | h_n(2,8,512) | c_n(2,8,512)
#define OUT_HN   8372224
#define OUT_CN   8380416

// ws layout (bytes). zx = seglen*65536 B.
// seglen=128  -> total 25,218,944 B (within R13-proven 25.2 MB budget)
// seglen=1024 -> total 83,939,328 B (used only if ws_size allows)
#define WS_FLAGS 0
#define WS_CSB   4096
#define WS_HSB0  36864
#define WS_HSB1  8433664
#define WS_ZX    16830464

__device__ __forceinline__ u16 f2bf(float f) {
  uint32_t u = __float_as_uint(f);
  u += 0x7FFFu + ((u >> 16) & 1u);
  return (u16)(u >> 16);
}
__device__ __forceinline__ float bf2f(u16 v) {
  return __uint_as_float(((uint32_t)v) << 16);
}
__device__ __forceinline__ short8v cvt8(const float* p) {
  float4 a = *(const float4*)p;
  float4 b = *(const float4*)(p + 4);
  short8v r;
  r[0] = (short)f2bf(a.x); r[1] = (short)f2bf(a.y);
  r[2] = (short)f2bf(a.z); r[3] = (short)f2bf(a.w);
  r[4] = (short)f2bf(b.x); r[5] = (short)f2bf(b.y);
  r[6] = (short)f2bf(b.z); r[7] = (short)f2bf(b.w);
  return r;
}

__global__ void k_init(uint32_t* flags) {
  if (threadIdx.x < 64) flags[threadIdx.x] = 0;
}

// zero h col 0 (both dirs) and c state
__global__ void k_zero(u16* h0, u16* h1, float* c) {
  int i = blockIdx.x * blockDim.x + threadIdx.x;   // 8192 threads
  if (i < 4096) { h0[i] = 0; h1[i] = 0; }
  if (i < 8192) c[i] = 0.f;
}

// stage x col tcol into swizzled xL (R13-proven pattern)
#define STAGE_X(tcol)                                                          \
  {                                                                            \
    _Pragma("unroll")                                                          \
    for (int half = 0; half < 2; ++half) {                                     \
      int g = tid + half * 256;                                                \
      int r = g >> 6, B = g & 63;                                              \
      const float* xr = xf + ((size_t)r * 1024 + (tcol)) * 512 + B * 8;        \
      float4 a = *(const float4*)xr;                                           \
      float4 b = *(const float4*)(xr + 4);                                     \
      short8v v;                                                               \
      v[0] = (short)f2bf(a.x); v[1] = (short)f2bf(a.y);                        \
      v[2] = (short)f2bf(a.z); v[3] = (short)f2bf(a.w);                        \
      v[4] = (short)f2bf(b.x); v[5] = (short)f2bf(b.y);                        \
      v[6] = (short)f2bf(b.z); v[7] = (short)f2bf(b.w);                        \
      *(short8v*)(xL + r * 512 + ((B ^ r) << 3)) = v;                          \
    }                                                                          \
  }

// Precompute zx[dir][sidx][wg][b*128 + g*32 + j] (bf16) for steps
// [s0, s0+seglen). Full-GPU batch GEMM — reuses the R13-proven x-projection
// machinery. One block = one (dir, wg, 32-step chunk).
__global__ void k_zx(const float* __restrict__ xf,
                     const float* __restrict__ wihf, const float* __restrict__ wihb,
                     u16* __restrict__ zx, int s0, int seglen)
{
  const int nch  = seglen >> 5;
  const int bid  = blockIdx.x;
  const int chunk = bid % nch;
  const int wg   = (bid / nch) & 15;
  const int dir  = bid / (nch * 16);
  const int tid  = threadIdx.x;
  const int wid  = tid >> 6;
  const int lane = tid & 63;
  const int jbase = wg * 32;
  const float* wih = dir ? wihb : wihf;

  __shared__ u16 xL[8 * 512];
  __shared__ float zL[4 * 8 * 32];

  // B-fragments from f32 (in-register conversion)
  short8v bih[2][16];
  {
    const int rr = lane & 15;
    const int ko = (lane >> 4) * 8;
    #pragma unroll
    for (int nt = 0; nt < 2; ++nt) {
      const int row = wid * 512 + jbase + nt * 16 + rr;
      #pragma unroll
      for (int kt = 0; kt < 16; ++kt)
        bih[nt][kt] = cvt8(wih + (size_t)row * 512 + kt * 32 + ko);
    }
  }

  const int rB = lane & 7;
  const int q  = lane >> 4;
  const f32x4 fzero = {0.f, 0.f, 0.f, 0.f};

  for (int i = 0; i < 32; ++i) {
    const int sidx = chunk * 32 + i;
    const int gstep = s0 + sidx;
    const int tn = dir ? (1023 - gstep) : gstep;
    STAGE_X(tn);
    __syncthreads();
    f32x4 acc0 = fzero, acc1 = fzero;
    #pragma unroll
    for (int kt = 0; kt < 16; ++kt) {
      short8v ax = *(const short8v*)(xL + rB * 512 + (((kt * 4 + q) ^ rB) << 3));
      acc0 = __builtin_amdgcn_mfma_f32_16x16x32_bf16(ax, bih[0][kt], acc0, 0, 0, 0);
      acc1 = __builtin_amdgcn_mfma_f32_16x16x32_bf16(ax, bih[1][kt], acc1, 0, 0, 0);
    }
    if (lane < 32) {
      #pragma unroll
      for (int r = 0; r < 4; ++r) {
        const int brow = (lane >> 4) * 4 + r;
        zL[wid * 256 + brow * 32 + (lane & 15)]      = acc0[r];
        zL[wid * 256 + brow * 32 + 16 + (lane & 15)] = acc1[r];
      }
    }
    __syncthreads();
    if (tid < 128) {
      const int b = tid >> 4;
      const int r = (tid & 15) * 8;     // position within [128] = g*32 + jj
      const int g = r >> 5;
      const int jj = r & 31;
      short8v v;
      #pragma unroll
      for (int w = 0; w < 8; ++w) v[w] = (short)f2bf(zL[g * 256 + b * 32 + jj + w]);
      *(short8v*)(zx + (((size_t)dir * seglen + sidx) * 16 + wg) * 1024 + tid * 8) = v;
    }
    __syncthreads();
  }
}

// Persistent bidirectional LSTM over steps [s0, s1). 32 blocks x 256 thr.
// Per step: prefetch zx slice (overlaps poll) -> poll -> atomic h column
// load -> h MFMAs -> route -> gates (h-part + zx + bias) -> atomic publish.
// x-projection fully removed from the recurrence chain (precomputed by k_zx).
__launch_bounds__(256, 1)
__global__ void k_lstm(const float* __restrict__ whhf, const float* __restrict__ whhb,
                       const float* __restrict__ bias0, const float* __restrict__ bias1,
                       const u16* __restrict__ zx,
                       u16* hsb0, u16* hsb1, float* csb, float* out,
                       uint32_t* flags, int s0, int s1, int seglen)
{
  const int tid  = threadIdx.x;
  const int wid  = tid >> 6;     // wave = gate
  const int lane = tid & 63;
  const int dir  = blockIdx.x >> 4;
  const int wg   = blockIdx.x & 15;
  const int jbase = wg * 32;

  const float* whh  = dir ? whhb : whhf;
  const float* bias = dir ? bias1 : bias0;
  u16* hsb = dir ? hsb1 : hsb0;
  uint32_t* fl = flags + dir * 16;

  __shared__ u16 hL[8 * 512];        // swizzled h column tile (8 KB)
  __shared__ float zL[4 * 8 * 32];   // [gate][b][jj]
  __shared__ u16 hS[8 * 32];         // this WG's h slice
  __shared__ u64 zxL[256];           // zx slice for current step (2 KB)

  // W_hh B-fragments from f32 (one-time, in-register conversion)
  short8v bhh[2][16];
  {
    const int rr = lane & 15;
    const int ko = (lane >> 4) * 8;
    #pragma unroll
    for (int nt = 0; nt < 2; ++nt) {
      const int row = wid * 512 + jbase + nt * 16 + rr;
      #pragma unroll
      for (int kt = 0; kt < 16; ++kt)
        bhh[nt][kt] = cvt8(whh + (size_t)row * 512 + kt * 32 + ko);
    }
  }

  const int cb = tid >> 5;
  const int cj = tid & 31;
  const float bz0 = bias[0 * 512 + jbase + cj];
  const float bz1 = bias[1 * 512 + jbase + cj];
  const float bz2 = bias[2 * 512 + jbase + cj];
  const float bz3 = bias[3 * 512 + jbase + cj];
  float* cp = csb + dir * 4096 + cb * 512 + jbase + cj;
  float c_state = *cp;               // zeroed by k_zero; carried across segments

  const int rB = lane & 7;
  const int q  = lane >> 4;
  const f32x4 fzero = {0.f, 0.f, 0.f, 0.f};
  const u16* zx16 = (const u16*)zxL;

  for (int gstep = s0; gstep < s1; ++gstep) {
    // prefetch this step's zx slice (no dependency on flags; overlaps poll)
    {
      const u64* zp = (const u64*)(zx + (((size_t)dir * seglen + (gstep - s0)) * 16 + wg) * 1024);
      zxL[tid] = zp[tid];
    }
    // relaxed agent poll (LLC-serviced); bounded
    if (tid < 16) {
      int guard = 0;
      while (__hip_atomic_load(&fl[tid], __ATOMIC_RELAXED, __HIP_MEMORY_SCOPE_AGENT)
             < (uint32_t)gstep && ++guard < (1 << 15)) { }
    }
    __syncthreads();
    // bulk h-column load via relaxed atomic u64, scatter into swizzled hL
    {
      const u64* hc = (const u64*)(hsb + (size_t)gstep * 4096);
      u64 d0 = __hip_atomic_load(hc + 4 * tid + 0, __ATOMIC_RELAXED, __HIP_MEMORY_SCOPE_AGENT);
      u64 d1 = __hip_atomic_load(hc + 4 * tid + 1, __ATOMIC_RELAXED, __HIP_MEMORY_SCOPE_AGENT);
      u64 d2 = __hip_atomic_load(hc + 4 * tid + 2, __ATOMIC_RELAXED, __HIP_MEMORY_SCOPE_AGENT);
      u64 d3 = __hip_atomic_load(hc + 4 * tid + 3, __ATOMIC_RELAXED, __HIP_MEMORY_SCOPE_AGENT);
      union { u64 qq[2]; short8v v; } p0, p1;
      p0.qq[0] = d0; p0.qq[1] = d1;
      p1.qq[0] = d2; p1.qq[1] = d3;
      int G0 = 2 * tid, G1 = 2 * tid + 1;
      int r0 = G0 >> 6, B0 = G0 & 63;
      int r1 = G1 >> 6, B1 = G1 & 63;
      *(short8v*)(hL + r0 * 512 + ((B0 ^ r0) << 3)) = p0.v;
      *(short8v*)(hL + r1 * 512 + ((B1 ^ r1) << 3)) = p1.v;
    }
    __syncthreads();
    // h-projection from LDS (critical path)
    f32x4 acc0 = fzero, acc1 = fzero;
    #pragma unroll
    for (int kt = 0; kt < 16; ++kt) {
      short8v ah = *(const short8v*)(hL + rB * 512 + (((kt * 4 + q) ^ rB) << 3));
      acc0 = __builtin_amdgcn_mfma_f32_16x16x32_bf16(ah, bhh[0][kt], acc0, 0, 0, 0);
      acc1 = __builtin_amdgcn_mfma_f32_16x16x32_bf16(ah, bhh[1][kt], acc1, 0, 0, 0);
    }
    if (lane < 32) {
      #pragma unroll
      for (int r = 0; r < 4; ++r) {
        const int brow = (lane >> 4) * 4 + r;
        zL[wid * 256 + brow * 32 + (lane & 15)]      = acc0[r];
        zL[wid * 256 + brow * 32 + 16 + (lane & 15)] = acc1[r];
      }
    }
    __syncthreads();
    // gates: z = h-part (zL) + precomputed x-part (zxL) + bias
    {
      float zi = zL[0 * 256 + cb * 32 + cj] + bz0 + bf2f(zx16[cb * 128 +  0 + cj]);
      float zf = zL[1 * 256 + cb * 32 + cj] + bz1 + bf2f(zx16[cb * 128 + 32 + cj]);
      float zg = zL[2 * 256 + cb * 32 + cj] + bz2 + bf2f(zx16[cb * 128 + 64 + cj]);
      float zo = zL[3 * 256 + cb * 32 + cj] + bz3 + bf2f(zx16[cb * 128 + 96 + cj]);
      float si = 1.f / (1.f + __expf(-zi));
      float sf = 1.f / (1.f + __expf(-zf));
      float so = 1.f / (1.f + __expf(-zo));
      float ag = fabsf(zg); float eg = __expf(-2.f * ag);
      float tg = (1.f - eg) / (1.f + eg); tg = copysignf(tg, zg);
      c_state = sf * c_state + si * tg;
      float ac = fabsf(c_state); float ec = __expf(-2.f * ac);
      float tc = (1.f - ec) / (1.f + ec); tc = copysignf(tc, c_state);
      float h = so * tc;
      hS[cb * 32 + cj] = f2bf(h);
      if (gstep == 1023) {
        out[OUT_HN + dir * 4096 + cb * 512 + jbase + cj] = h;
        out[OUT_CN + dir * 4096 + cb * 512 + jbase + cj] = c_state;
      }
    }
    __syncthreads();
    // wave 0: publish h slice as write-through atomics, then flag
    if (tid < 64) {
      const int pb = tid >> 3;
      const int pt = tid & 7;
      u64 hv = *(const u64*)(hS + pb * 32 + 4 * pt);
      u64* dst = (u64*)(hsb + ((size_t)(gstep + 1) * 8 + pb) * 512 + jbase + 4 * pt);
      __hip_atomic_store(dst, hv, __ATOMIC_RELAXED, __HIP_MEMORY_SCOPE_AGENT);
      asm volatile("s_waitcnt vmcnt(0)" ::: "memory");  // slice at LLC
    }
    if (tid == 0) {
      __hip_atomic_store(&fl[wg], (uint32_t)(gstep + 1), __ATOMIC_RELAXED,
                         __HIP_MEMORY_SCOPE_AGENT);
    }
  }
  *cp = c_state;   // carry c across segments
}

// Neighbor-average epilogue — R9-proven (order is int32 on device).
__global__ void k_combine(const u16* __restrict__ hsb0, const u16* __restrict__ hsb1,
                          const int* __restrict__ cidx, const int* __restrict__ cmask,
                          const int* __restrict__ order, float* __restrict__ out)
{
  const int tid = threadIdx.x;
  const int b = blockIdx.x / 1022;
  const int s = 1 + (blockIdx.x % 1022);
  __shared__ int sidx[8];
  __shared__ float smask[8];
  __shared__ int rsh;
  if (tid == 0) rsh = order[b];
  __syncthreads();
  const int r = rsh;
  if (tid < 8) {
    size_t base = ((size_t)r * 1024 + s) * 8 + tid;
    sidx[tid] = cidx[base];
    smask[tid] = (float)cmask[base];
  }
  __syncthreads();
  float cnt = 0.f;
  #pragma unroll
  for (int k = 0; k < 8; ++k) cnt += smask[k];
  const float inv = 1.f / (1.f + cnt);

  const int col0 = tid * 4;
  const bool isF = col0 < 512;
  const int cloc = isF ? col0 : col0 - 512;
  const u16* hb = isF ? hsb0 : hsb1;

  float v0, v1, v2, v3;
  {
    size_t ci2 = isF ? (size_t)(s + 1) : (size_t)(1024 - s);
    ushort4 qv = *(const ushort4*)(hb + (ci2 * 8 + b) * 512 + cloc);
    v0 = bf2f(qv.x); v1 = bf2f(qv.y); v2 = bf2f(qv.z); v3 = bf2f(qv.w);
  }
  #pragma unroll
  for (int k = 0; k < 8; ++k) {
    float m = smask[k];
    if (m != 0.f) {
      int sp = sidx[k];
      size_t ci2 = isF ? (size_t)(sp + 1) : (size_t)(1024 - sp);
      ushort4 qv = *(const ushort4*)(hb + (ci2 * 8 + b) * 512 + cloc);
      v0 += m * bf2f(qv.x); v1 += m * bf2f(qv.y); v2 += m * bf2f(qv.z); v3 += m * bf2f(qv.w);
    }
  }
  size_t ob = ((size_t)r * 1022 + (s - 1)) * 1024 + col0;
  float4 ov; ov.x = v0 * inv; ov.y = v1 * inv; ov.z = v2 * inv; ov.w = v3 * inv;
  *(float4*)(out + ob) = ov;
}

extern "C" void kernel_launch(void* const* d_in, const int* in_sizes, int n_in,
                              void* d_out, int out_size, void* d_ws, size_t ws_size,
                              hipStream_t stream)
{
  const float* x      = (const float*)d_in[0];
  const int*   cidx   = (const int*)d_in[1];
  const int*   cmask  = (const int*)d_in[2];
  const int*   order  = (const int*)d_in[3];   // int64 in reference -> int32 on device
  const float* wihf = (const float*)d_in[4];
  const float* whhf = (const float*)d_in[5];
  const float* bf   = (const float*)d_in[6];
  const float* wihb = (const float*)d_in[7];
  const float* whhb = (const float*)d_in[8];
  const float* bb   = (const float*)d_in[9];
  float* out = (float*)d_out;

  char* ws = (char*)d_ws;
  uint32_t* FLAGS = (uint32_t*)(ws + WS_FLAGS);
  float* CSB = (float*)(ws + WS_CSB);
  u16* HSB0 = (u16*)(ws + WS_HSB0);
  u16* HSB1 = (u16*)(ws + WS_HSB1);
  u16* ZX   = (u16*)(ws + WS_ZX);

  // adapt zx segment length to the available workspace
  const int seglen = (ws_size >= (size_t)WS_ZX + 1024ull * 65536) ? 1024 : 128;

  hipLaunchKernelGGL(k_init, dim3(1), dim3(64), 0, stream, FLAGS);
  hipLaunchKernelGGL(k_zero, dim3(32), dim3(256), 0, stream, HSB0, HSB1, CSB);

  for (int s0 = 0; s0 < 1024; s0 += seglen) {
    hipLaunchKernelGGL(k_zx, dim3(2 * 16 * (seglen >> 5)), dim3(256), 0, stream,
                       x, wihf, wihb, ZX, s0, seglen);
    hipLaunchKernelGGL(k_lstm, dim3(32), dim3(256), 0, stream,
                       whhf, whhb, bf, bb, ZX, HSB0, HSB1, CSB, out, FLAGS,
                       s0, s0 + seglen, seglen);
  }

  hipLaunchKernelGGL(k_combine, dim3(8 * 1022), dim3(256), 0, stream,
                     HSB0, HSB1, cidx, cmask, order, out);
}